// Round 4
// baseline (398.856 us; speedup 1.0000x reference)
//
#include <hip/hip_runtime.h>
#include <hip/hip_bf16.h>

// Problem constants (single-level MSDeformAttn)
#define BS     2
#define H_LVL  257
#define W_LVL  512
#define NQC    (H_LVL * W_LVL)   // 131584
#define DD     128
#define HEADS  8
#define PTS    4
#define DH     16
#define MTOT   (BS * NQC)        // 263168

typedef float v4f __attribute__((ext_vector_type(4)));
typedef short v8s __attribute__((ext_vector_type(8)));

static __device__ __forceinline__ unsigned short f2bb(float f) {
    union { float f; unsigned int u; } v; v.f = f;
    const unsigned int u = v.u;
    return (unsigned short)((u + 0x7fffu + ((u >> 16) & 1u)) >> 16);  // RNE
}
static __device__ __forceinline__ float bb2f(unsigned short h) {
    union { unsigned int u; float f; } v; v.u = ((unsigned int)h) << 16;
    return v.f;
}
static __device__ __forceinline__ void fma4(float4& acc, float w, const unsigned short* p) {
    const ushort4 r = *(const ushort4*)p;
    acc.x = fmaf(w, bb2f(r.x), acc.x);
    acc.y = fmaf(w, bb2f(r.y), acc.y);
    acc.z = fmaf(w, bb2f(r.z), acc.z);
    acc.w = fmaf(w, bb2f(r.w), acc.w);
}

// ---------------------------------------------------------------------------
// prep: build Wt224 = [value(128) | off(64) | attn(32)] rows, k-contiguous bf16;
// WtO for the output proj; bcat224 = [bv | boff | battn].
// ---------------------------------------------------------------------------
__global__ __launch_bounds__(256) void prep_kernel(
    const float* __restrict__ Wv, const float* __restrict__ bv,
    const float* __restrict__ Woff, const float* __restrict__ boff,
    const float* __restrict__ Wattn, const float* __restrict__ battn,
    const float* __restrict__ Wout,
    unsigned short* __restrict__ Wt224, unsigned short* __restrict__ WtO,
    float* __restrict__ bcat224)
{
    const int id = blockIdx.x * 256 + threadIdx.x;   // 112 blocks: 0..28671
    {
        const int n = id >> 7, k = id & 127;
        float v;
        if (n < 128)      v = Wv[k * DD + n];
        else if (n < 192) v = Woff[k * 64 + (n - 128)];
        else              v = Wattn[k * 32 + (n - 192)];
        Wt224[id] = f2bb(v);
    }
    if (id < 128 * 128) {
        const int n = id >> 7, k = id & 127;
        WtO[id] = f2bb(Wout[k * DD + n]);
    }
    if (id < 224)
        bcat224[id] = (id < 128) ? bv[id] : (id < 192 ? boff[id - 128] : battn[id - 192]);
}

// ---------------------------------------------------------------------------
// Fused GEMM: [M,128] @ [128,224] — cols 0..127 -> value layout bf16,
// cols 128..223 -> proj [m][96] bf16. One query read instead of two.
// ---------------------------------------------------------------------------
__global__ __launch_bounds__(256) void gemm_fused_kernel(
    const float* __restrict__ A,
    const unsigned short* __restrict__ Wt,     // [224][128] bf16
    const float* __restrict__ bias,            // [224]
    unsigned short* __restrict__ value,        // [16][NQC][16] bf16
    unsigned short* __restrict__ proj)         // [M][96] bf16
{
    constexpr int NT = 14;
    constexpr int NC = NT * 16;                // 224
    __shared__ unsigned short As[64 * 136];
    __shared__ unsigned short Ws[NC * 136];
    const int t = threadIdx.x;
    const long long m0 = (long long)blockIdx.x * 64;

    // stage A: 64x128 fp32 -> bf16
    {
        const float4* src = (const float4*)(A + m0 * DD);
        #pragma unroll
        for (int rep = 0; rep < 8; ++rep) {
            const int c = rep * 256 + t;
            const int m = c >> 5, f4 = c & 31;
            const float4 v = src[c];
            ushort4 hq;
            hq.x = f2bb(v.x); hq.y = f2bb(v.y); hq.z = f2bb(v.z); hq.w = f2bb(v.w);
            *(ushort4*)(&As[m * 136 + f4 * 4]) = hq;
        }
    }
    // stage W: 224 x 128 bf16
    {
        const uint4* src = (const uint4*)Wt;
        #pragma unroll
        for (int rep = 0; rep < 14; ++rep) {
            const int c = rep * 256 + t;       // 3584 total
            const int n = c >> 4, kc = c & 15;
            *(uint4*)(&Ws[n * 136 + kc * 8]) = src[c];
        }
    }
    __syncthreads();

    const int lane = t & 63, wave = t >> 6;
    const int l15 = lane & 15, quad = lane >> 4;

    v4f acc[NT];
    #pragma unroll
    for (int nt = 0; nt < NT; ++nt) { v4f z = {0.f, 0.f, 0.f, 0.f}; acc[nt] = z; }

    const int arow = wave * 16 + l15;
    #pragma unroll
    for (int kk = 0; kk < 4; ++kk) {
        const v8s a = *(const v8s*)(&As[arow * 136 + kk * 32 + quad * 8]);
        #pragma unroll
        for (int nt = 0; nt < NT; ++nt) {
            const v8s b = *(const v8s*)(&Ws[(nt * 16 + l15) * 136 + kk * 32 + quad * 8]);
            acc[nt] = __builtin_amdgcn_mfma_f32_16x16x32_bf16(a, b, acc[nt], 0, 0, 0);
        }
    }

    const long long mbase = m0 + wave * 16 + quad * 4;
    const int b = (int)(m0 / NQC);             // 64 | NQC
    #pragma unroll
    for (int nt = 0; nt < 8; ++nt) {           // value: h = nt, dh = l15
        const float bi = bias[nt * 16 + l15];
        #pragma unroll
        for (int r = 0; r < 4; ++r) {
            const long long q = (mbase + r) - (long long)b * NQC;
            value[((long long)(b * HEADS + nt) * NQC + q) * DH + l15] =
                f2bb(acc[nt][r] + bi);
        }
    }
    #pragma unroll
    for (int nt = 8; nt < 14; ++nt) {          // proj cols (nt-8)*16 + l15
        const float bi = bias[nt * 16 + l15];
        #pragma unroll
        for (int r = 0; r < 4; ++r)
            proj[(mbase + r) * 96 + (nt - 8) * 16 + l15] = f2bb(acc[nt][r] + bi);
    }
}

// ---------------------------------------------------------------------------
// Legacy GEMM template (fallback path only). MODE 0: value-layout bf16 out.
// MODE 2: fp32 in-place + b + 2*query.
// ---------------------------------------------------------------------------
template<int NT, int MODE>
__global__ __launch_bounds__(256) void gemm_kernel(
    const float* __restrict__ A,
    const unsigned short* __restrict__ Wt,
    const float* __restrict__ bias,
    unsigned short* __restrict__ dst_bf,
    float* __restrict__ dst_f,
    const float* __restrict__ query)
{
    constexpr int NC = NT * 16;
    __shared__ unsigned short As[64 * 136];
    __shared__ unsigned short Ws[NC * 136];
    const int t = threadIdx.x;
    const long long m0 = (long long)blockIdx.x * 64;

    {
        const float4* src = (const float4*)(A + m0 * DD);
        #pragma unroll
        for (int rep = 0; rep < 8; ++rep) {
            const int c = rep * 256 + t;
            const int m = c >> 5, f4 = c & 31;
            const float4 v = src[c];
            ushort4 hq;
            hq.x = f2bb(v.x); hq.y = f2bb(v.y); hq.z = f2bb(v.z); hq.w = f2bb(v.w);
            *(ushort4*)(&As[m * 136 + f4 * 4]) = hq;
        }
    }
    {
        const uint4* src = (const uint4*)Wt;
        for (int c = t; c < NC * 16; c += 256) {
            const int n = c >> 4, kc = c & 15;
            *(uint4*)(&Ws[n * 136 + kc * 8]) = src[c];
        }
    }
    __syncthreads();

    const int lane = t & 63, wave = t >> 6;
    const int l15 = lane & 15, quad = lane >> 4;

    v4f acc[NT];
    #pragma unroll
    for (int nt = 0; nt < NT; ++nt) { v4f z = {0.f, 0.f, 0.f, 0.f}; acc[nt] = z; }

    const int arow = wave * 16 + l15;
    #pragma unroll
    for (int kk = 0; kk < 4; ++kk) {
        const v8s a = *(const v8s*)(&As[arow * 136 + kk * 32 + quad * 8]);
        #pragma unroll
        for (int nt = 0; nt < NT; ++nt) {
            const v8s b = *(const v8s*)(&Ws[(nt * 16 + l15) * 136 + kk * 32 + quad * 8]);
            acc[nt] = __builtin_amdgcn_mfma_f32_16x16x32_bf16(a, b, acc[nt], 0, 0, 0);
        }
    }

    const long long mbase = m0 + wave * 16 + quad * 4;
    if (MODE == 0) {
        const int b = (int)(m0 / NQC);
        #pragma unroll
        for (int nt = 0; nt < NT; ++nt) {
            const float bi = bias[nt * 16 + l15];
            #pragma unroll
            for (int r = 0; r < 4; ++r) {
                const long long q = (mbase + r) - (long long)b * NQC;
                dst_bf[((long long)(b * HEADS + nt) * NQC + q) * DH + l15] =
                    f2bb(acc[nt][r] + bi);
            }
        }
    } else {
        #pragma unroll
        for (int nt = 0; nt < NT; ++nt) {
            const float bi = bias[nt * 16 + l15];
            #pragma unroll
            for (int r = 0; r < 4; ++r) {
                const long long idx = (mbase + r) * DD + nt * 16 + l15;
                dst_f[idx] = acc[nt][r] + bi + 2.0f * query[idx];
            }
        }
    }
}

// ---------------------------------------------------------------------------
// Merged sampler + output GEMM. 4112 blocks x 256 threads, 64 queries/block.
// Phase 1: proj -> projF (LDS fp32). Phase 2: 8 gather iterations (each =
// old sampler block): params + softmax + bilinear gather -> bf16 attn tile
// As[64][136] in LDS (MFMA A layout). Phase 3: stage WtO over projF (union),
// MFMA vs Ws, write out = acc + bout + 2*query. Eliminates the 67.4 MB x2
// stash round-trip and one dispatch.
// LDS: union(projF 24.6 KB, Ws 34.8 KB) + As 17.4 KB = 52.2 KB -> 3 blocks/CU.
// ---------------------------------------------------------------------------
__global__ __launch_bounds__(256) void sample_out_kernel(
    const unsigned short* __restrict__ proj,   // [M][96] bf16
    const unsigned short* __restrict__ value,  // [16][NQC][16] bf16
    const unsigned short* __restrict__ WtO,    // [128][128] bf16 (n-major, k-contig)
    const float* __restrict__ bout,            // [128]
    const float* __restrict__ query,
    float* __restrict__ out)
{
    __shared__ union {
        float projF[64][96];                   // 24576 B (phase 1-2)
        unsigned short Ws[128 * 136];          // 34816 B (phase 3)
    } sh;
    __shared__ unsigned short As[64 * 136];    // 17408 B

    const int t = threadIdx.x;
    const long long qbase = (long long)blockIdx.x * 64;

    // ---- Phase 1: stage proj (64x96 bf16 -> fp32 LDS) ----
    {
        const ushort4* src = (const ushort4*)(proj + qbase * 96);
        #pragma unroll
        for (int rep = 0; rep < 6; ++rep) {    // 1536 ushort4
            const int i = rep * 256 + t;
            const ushort4 r = src[i];
            const int qq = (i * 4) / 96, c = (i * 4) % 96;   // 4 | 96: no straddle
            sh.projF[qq][c]     = bb2f(r.x);
            sh.projF[qq][c + 1] = bb2f(r.y);
            sh.projF[qq][c + 2] = bb2f(r.z);
            sh.projF[qq][c + 3] = bb2f(r.w);
        }
    }
    __syncthreads();

    // ---- Phase 2: gather. 2048 lane-tasks, 8 per thread ----
    const int b = (int)(qbase / NQC);          // 64 | NQC: no straddle
    const int lq = t & 31;
    const int h = lq >> 2, p_own = lq & 3;
    const int lbase = (t & 63) & ~3;
    const unsigned short* V = value + (size_t)(b * HEADS + h) * NQC * DH + p_own * 4;

    #pragma unroll
    for (int it = 0; it < 8; ++it) {
        const int q_loc = it * 8 + (t >> 5);
        const int qidx = (int)(qbase - (long long)b * NQC) + q_loc;
        const int row = qidx >> 9, col = qidx & 511;

        const float offx = sh.projF[q_loc][(h * PTS + p_own) * 2];
        const float offy = sh.projF[q_loc][(h * PTS + p_own) * 2 + 1];
        const float al   = sh.projF[q_loc][64 + h * PTS + p_own];
        float mx = fmaxf(al, __shfl_xor(al, 1));
        mx = fmaxf(mx, __shfl_xor(mx, 2));
        const float e = __expf(al - mx);
        float sm = e + __shfl_xor(e, 1);
        sm += __shfl_xor(sm, 2);
        const float aw = e / sm;

        const float x = (float)col * (1.0f / 511.0f) * (float)W_LVL + offx - 0.5f;
        const float y = (float)row * (1.0f / 256.0f) * (float)H_LVL + offy - 0.5f;
        const float x0f = floorf(x), y0f = floorf(y);
        const int x0 = (int)x0f, y0 = (int)y0f;
        const int x1 = x0 + 1, y1 = y0 + 1;
        const float wx1 = x - x0f, wx0 = 1.0f - wx1;
        const float wy1 = y - y0f, wy0 = 1.0f - wy1;
        const float vx0 = (x0 >= 0 && x0 < W_LVL) ? 1.f : 0.f;
        const float vx1 = (x1 >= 0 && x1 < W_LVL) ? 1.f : 0.f;
        const float vy0 = (y0 >= 0 && y0 < H_LVL) ? 1.f : 0.f;
        const float vy1 = (y1 >= 0 && y1 < H_LVL) ? 1.f : 0.f;
        float w00 = aw * wx0 * wy0 * vx0 * vy0;
        float w01 = aw * wx1 * wy0 * vx1 * vy0;
        float w10 = aw * wx0 * wy1 * vx0 * vy1;
        float w11 = aw * wx1 * wy1 * vx1 * vy1;
        const int xc0 = min(max(x0, 0), W_LVL - 1), xc1 = min(max(x1, 0), W_LVL - 1);
        const int yc0 = min(max(y0, 0), H_LVL - 1), yc1 = min(max(y1, 0), H_LVL - 1);
        int i00 = yc0 * W_LVL + xc0, i01 = yc0 * W_LVL + xc1;
        int i10 = yc1 * W_LVL + xc0, i11 = yc1 * W_LVL + xc1;

        float4 acc = {0.f, 0.f, 0.f, 0.f};
        #pragma unroll
        for (int p = 0; p < 4; ++p) {
            const int src = lbase + p;
            const float W00 = __shfl(w00, src, 64), W01 = __shfl(w01, src, 64);
            const float W10 = __shfl(w10, src, 64), W11 = __shfl(w11, src, 64);
            const int   I00 = __shfl(i00, src, 64), I01 = __shfl(i01, src, 64);
            const int   I10 = __shfl(i10, src, 64), I11 = __shfl(i11, src, 64);
            fma4(acc, W00, V + (size_t)I00 * DH);
            fma4(acc, W01, V + (size_t)I01 * DH);
            fma4(acc, W10, V + (size_t)I10 * DH);
            fma4(acc, W11, V + (size_t)I11 * DH);
        }
        ushort4 h4;
        h4.x = f2bb(acc.x); h4.y = f2bb(acc.y); h4.z = f2bb(acc.z); h4.w = f2bb(acc.w);
        *(ushort4*)(&As[q_loc * 136 + h * 16 + p_own * 4]) = h4;
    }
    __syncthreads();

    // ---- Phase 3: stage WtO over projF (safe: all projF reads done) ----
    {
        const uint4* src = (const uint4*)WtO;
        #pragma unroll
        for (int rep = 0; rep < 8; ++rep) {
            const int c = rep * 256 + t;       // 2048 total
            const int n = c >> 4, kc = c & 15;
            *(uint4*)(&sh.Ws[n * 136 + kc * 8]) = src[c];
        }
    }
    __syncthreads();

    // ---- MFMA: out[64,128] = As @ WtO^T(+bias+2q) ----
    const int lane = t & 63, wave = t >> 6;
    const int l15 = lane & 15, quad = lane >> 4;

    v4f acc[8];
    #pragma unroll
    for (int nt = 0; nt < 8; ++nt) { v4f z = {0.f, 0.f, 0.f, 0.f}; acc[nt] = z; }

    const int arow = wave * 16 + l15;
    #pragma unroll
    for (int kk = 0; kk < 4; ++kk) {
        const v8s a = *(const v8s*)(&As[arow * 136 + kk * 32 + quad * 8]);
        #pragma unroll
        for (int nt = 0; nt < 8; ++nt) {
            const v8s bfr = *(const v8s*)(&sh.Ws[(nt * 16 + l15) * 136 + kk * 32 + quad * 8]);
            acc[nt] = __builtin_amdgcn_mfma_f32_16x16x32_bf16(a, bfr, acc[nt], 0, 0, 0);
        }
    }

    const long long mbase = qbase + wave * 16 + quad * 4;
    #pragma unroll
    for (int nt = 0; nt < 8; ++nt) {
        const float bi = bout[nt * 16 + l15];
        #pragma unroll
        for (int r = 0; r < 4; ++r) {
            const long long idx = (mbase + r) * DD + nt * 16 + l15;
            out[idx] = acc[nt][r] + bi + 2.0f * query[idx];
        }
    }
}

// ---------------------------------------------------------------------------
// Fallback sampler (no precomp workspace): fp32 out, on-the-fly proj.
// ---------------------------------------------------------------------------
__global__ __launch_bounds__(256) void sample2_fb_kernel(
    const float* __restrict__ query,
    const float* __restrict__ Woff, const float* __restrict__ boff,
    const float* __restrict__ Wattn, const float* __restrict__ battn,
    const unsigned short* __restrict__ value,  // [16][NQC][16] bf16
    float* __restrict__ attn_out)
{
    __shared__ float projF[8][96];
    const int t = threadIdx.x;
    const long long qbase = (long long)blockIdx.x * 8;

    __shared__ float qs[8][DD];
    {
        const int qi = t >> 5, k4 = (t & 31) * 4;
        const float4 v = *(const float4*)(query + (qbase + qi) * DD + k4);
        qs[qi][k4] = v.x; qs[qi][k4 + 1] = v.y; qs[qi][k4 + 2] = v.z; qs[qi][k4 + 3] = v.w;
    }
    __syncthreads();
    for (int task = t; task < 768; task += 256) {
        const int qi = task / 96, c = task % 96;
        float a; const float* wp; int stride;
        if (c < 64) { a = boff[c];       wp = Woff  + c;        stride = 64; }
        else        { a = battn[c - 64]; wp = Wattn + (c - 64); stride = 32; }
        for (int k = 0; k < DD; ++k) a += qs[qi][k] * wp[k * stride];
        projF[qi][c] = a;
    }
    __syncthreads();

    const int q_loc = t >> 5, lq = t & 31;
    const int h = lq >> 2, p_own = lq & 3;
    const long long bq = qbase + q_loc;
    const int b = (int)(bq / NQC);
    const int qidx = (int)(bq - (long long)b * NQC);
    const int row = qidx >> 9, col = qidx & 511;

    const float offx = projF[q_loc][(h * PTS + p_own) * 2];
    const float offy = projF[q_loc][(h * PTS + p_own) * 2 + 1];
    const float al   = projF[q_loc][64 + h * PTS + p_own];
    float mx = fmaxf(al, __shfl_xor(al, 1));
    mx = fmaxf(mx, __shfl_xor(mx, 2));
    const float e = __expf(al - mx);
    float sm = e + __shfl_xor(e, 1);
    sm += __shfl_xor(sm, 2);
    const float aw = e / sm;

    const float x = (float)col * (1.0f / 511.0f) * (float)W_LVL + offx - 0.5f;
    const float y = (float)row * (1.0f / 256.0f) * (float)H_LVL + offy - 0.5f;
    const float x0f = floorf(x), y0f = floorf(y);
    const int x0 = (int)x0f, y0 = (int)y0f;
    const int x1 = x0 + 1, y1 = y0 + 1;
    const float wx1 = x - x0f, wx0 = 1.0f - wx1;
    const float wy1 = y - y0f, wy0 = 1.0f - wy1;
    const float vx0 = (x0 >= 0 && x0 < W_LVL) ? 1.f : 0.f;
    const float vx1 = (x1 >= 0 && x1 < W_LVL) ? 1.f : 0.f;
    const float vy0 = (y0 >= 0 && y0 < H_LVL) ? 1.f : 0.f;
    const float vy1 = (y1 >= 0 && y1 < H_LVL) ? 1.f : 0.f;
    float w00 = aw * wx0 * wy0 * vx0 * vy0;
    float w01 = aw * wx1 * wy0 * vx1 * vy0;
    float w10 = aw * wx0 * wy1 * vx0 * vy1;
    float w11 = aw * wx1 * wy1 * vx1 * vy1;
    const int xc0 = min(max(x0, 0), W_LVL - 1), xc1 = min(max(x1, 0), W_LVL - 1);
    const int yc0 = min(max(y0, 0), H_LVL - 1), yc1 = min(max(y1, 0), H_LVL - 1);
    int i00 = yc0 * W_LVL + xc0, i01 = yc0 * W_LVL + xc1;
    int i10 = yc1 * W_LVL + xc0, i11 = yc1 * W_LVL + xc1;

    const int dq4 = p_own;
    const unsigned short* V = value + (size_t)(b * HEADS + h) * NQC * DH + dq4 * 4;
    float4 acc = {0.f, 0.f, 0.f, 0.f};
    const int lbase = (t & 63) & ~3;
    #pragma unroll
    for (int p = 0; p < 4; ++p) {
        const int src = lbase + p;
        const float W00 = __shfl(w00, src, 64), W01 = __shfl(w01, src, 64);
        const float W10 = __shfl(w10, src, 64), W11 = __shfl(w11, src, 64);
        const int   I00 = __shfl(i00, src, 64), I01 = __shfl(i01, src, 64);
        const int   I10 = __shfl(i10, src, 64), I11 = __shfl(i11, src, 64);
        fma4(acc, W00, V + (size_t)I00 * DH);
        fma4(acc, W01, V + (size_t)I01 * DH);
        fma4(acc, W10, V + (size_t)I10 * DH);
        fma4(acc, W11, V + (size_t)I11 * DH);
    }
    *(float4*)(attn_out + bq * DD + h * DH + dq4 * 4) = acc;
}

// ---------------------------------------------------------------------------
extern "C" void kernel_launch(void* const* d_in, const int* in_sizes, int n_in,
                              void* d_out, int out_size, void* d_ws, size_t ws_size,
                              hipStream_t stream) {
    const float* query = (const float*)d_in[0];
    const float* Wv    = (const float*)d_in[1];
    const float* bv    = (const float*)d_in[2];
    const float* Woff  = (const float*)d_in[3];
    const float* boff  = (const float*)d_in[4];
    const float* Wattn = (const float*)d_in[5];
    const float* battn = (const float*)d_in[6];
    const float* Wout  = (const float*)d_in[7];
    const float* bout  = (const float*)d_in[8];
    float* out = (float*)d_out;

    char* ws = (char*)d_ws;
    size_t off = 0;
    unsigned short* Wt224 = (unsigned short*)(ws + off); off += 224 * 128 * 2;
    unsigned short* WtO   = (unsigned short*)(ws + off); off += 128 * 128 * 2;
    float*          bcat  = (float*)(ws + off);          off += 224 * 4;
    off = (off + 255) & ~(size_t)255;
    unsigned short* value = (unsigned short*)(ws + off);
    off += (size_t)BS * HEADS * NQC * DH * 2;            // 67,371,008 B
    off = (off + 255) & ~(size_t)255;
    unsigned short* proj = (unsigned short*)(ws + off);
    const size_t proj_need = (size_t)MTOT * 96 * 2;      // 50,528,256 B
    const bool precomp = (ws_size >= off + proj_need);

    prep_kernel<<<112, 256, 0, stream>>>(Wv, bv, Woff, boff, Wattn, battn, Wout,
                                         Wt224, WtO, bcat);
    if (precomp) {
        gemm_fused_kernel<<<MTOT / 64, 256, 0, stream>>>(query, Wt224, bcat, value, proj);
        sample_out_kernel<<<MTOT / 64, 256, 0, stream>>>(proj, value, WtO, bout, query, out);
    } else {
        gemm_kernel<8, 0><<<MTOT / 64, 256, 0, stream>>>(query, Wt224, bcat, value,
                                                         nullptr, nullptr);
        sample2_fb_kernel<<<MTOT / 8, 256, 0, stream>>>(query, Woff, boff,
                                                        Wattn, battn, value, out);
        gemm_kernel<8, 2><<<MTOT / 64, 256, 0, stream>>>(out, WtO, bout, nullptr, out, query);
    }
}

// Round 5
// 381.571 us; speedup vs baseline: 1.0453x; 1.0453x over previous
//
#include <hip/hip_runtime.h>
#include <hip/hip_bf16.h>

// Problem constants (single-level MSDeformAttn)
#define BS     2
#define H_LVL  257
#define W_LVL  512
#define NQC    (H_LVL * W_LVL)   // 131584
#define DD     128
#define HEADS  8
#define PTS    4
#define DH     16
#define MTOT   (BS * NQC)        // 263168

typedef float v4f __attribute__((ext_vector_type(4)));
typedef short v8s __attribute__((ext_vector_type(8)));

static __device__ __forceinline__ unsigned short f2bb(float f) {
    union { float f; unsigned int u; } v; v.f = f;
    const unsigned int u = v.u;
    return (unsigned short)((u + 0x7fffu + ((u >> 16) & 1u)) >> 16);  // RNE
}
static __device__ __forceinline__ float bb2f(unsigned short h) {
    union { unsigned int u; float f; } v; v.u = ((unsigned int)h) << 16;
    return v.f;
}
static __device__ __forceinline__ void fma4(float4& acc, float w, const unsigned short* p) {
    const ushort4 r = *(const ushort4*)p;
    acc.x = fmaf(w, bb2f(r.x), acc.x);
    acc.y = fmaf(w, bb2f(r.y), acc.y);
    acc.z = fmaf(w, bb2f(r.z), acc.z);
    acc.w = fmaf(w, bb2f(r.w), acc.w);
}

// ---------------------------------------------------------------------------
// prep: Wt224 = [value(128) | off(64) | attn(32)] rows k-contiguous bf16;
// WtO (n-major, fallback path); WtOf (MFMA fragment order for merged kernel);
// bcat224 = [bv | boff | battn].
// WtOf layout: id = ((kk*8+nt)*64 + lane)*8 + j  ->  Wout[k*DD+n] with
//   n = nt*16 + (lane&15), k = kk*32 + (lane>>4)*8 + j.
// ---------------------------------------------------------------------------
__global__ __launch_bounds__(256) void prep_kernel(
    const float* __restrict__ Wv, const float* __restrict__ bv,
    const float* __restrict__ Woff, const float* __restrict__ boff,
    const float* __restrict__ Wattn, const float* __restrict__ battn,
    const float* __restrict__ Wout,
    unsigned short* __restrict__ Wt224, unsigned short* __restrict__ WtO,
    unsigned short* __restrict__ WtOf, float* __restrict__ bcat224)
{
    const int id = blockIdx.x * 256 + threadIdx.x;   // 112 blocks: 0..28671
    {
        const int n = id >> 7, k = id & 127;
        float v;
        if (n < 128)      v = Wv[k * DD + n];
        else if (n < 192) v = Woff[k * 64 + (n - 128)];
        else              v = Wattn[k * 32 + (n - 192)];
        Wt224[id] = f2bb(v);
    }
    if (id < 128 * 128) {
        const int n = id >> 7, k = id & 127;
        WtO[id] = f2bb(Wout[k * DD + n]);
    }
    if (id < 128 * 128) {
        const int j = id & 7, l = (id >> 3) & 63, nt = (id >> 9) & 7, kk = id >> 12;
        const int n = nt * 16 + (l & 15);
        const int k = kk * 32 + (l >> 4) * 8 + j;
        WtOf[id] = f2bb(Wout[k * DD + n]);
    }
    if (id < 224)
        bcat224[id] = (id < 128) ? bv[id] : (id < 192 ? boff[id - 128] : battn[id - 192]);
}

// ---------------------------------------------------------------------------
// Fused GEMM: [M,128] @ [128,224] — cols 0..127 -> value layout bf16,
// cols 128..223 -> proj [m][96] bf16. One query read instead of two.
// ---------------------------------------------------------------------------
__global__ __launch_bounds__(256) void gemm_fused_kernel(
    const float* __restrict__ A,
    const unsigned short* __restrict__ Wt,     // [224][128] bf16
    const float* __restrict__ bias,            // [224]
    unsigned short* __restrict__ value,        // [16][NQC][16] bf16
    unsigned short* __restrict__ proj)         // [M][96] bf16
{
    constexpr int NT = 14;
    constexpr int NC = NT * 16;                // 224
    __shared__ unsigned short As[64 * 136];
    __shared__ unsigned short Ws[NC * 136];
    const int t = threadIdx.x;
    const long long m0 = (long long)blockIdx.x * 64;

    // stage A: 64x128 fp32 -> bf16
    {
        const float4* src = (const float4*)(A + m0 * DD);
        #pragma unroll
        for (int rep = 0; rep < 8; ++rep) {
            const int c = rep * 256 + t;
            const int m = c >> 5, f4 = c & 31;
            const float4 v = src[c];
            ushort4 hq;
            hq.x = f2bb(v.x); hq.y = f2bb(v.y); hq.z = f2bb(v.z); hq.w = f2bb(v.w);
            *(ushort4*)(&As[m * 136 + f4 * 4]) = hq;
        }
    }
    // stage W: 224 x 128 bf16
    {
        const uint4* src = (const uint4*)Wt;
        #pragma unroll
        for (int rep = 0; rep < 14; ++rep) {
            const int c = rep * 256 + t;       // 3584 total
            const int n = c >> 4, kc = c & 15;
            *(uint4*)(&Ws[n * 136 + kc * 8]) = src[c];
        }
    }
    __syncthreads();

    const int lane = t & 63, wave = t >> 6;
    const int l15 = lane & 15, quad = lane >> 4;

    v4f acc[NT];
    #pragma unroll
    for (int nt = 0; nt < NT; ++nt) { v4f z = {0.f, 0.f, 0.f, 0.f}; acc[nt] = z; }

    const int arow = wave * 16 + l15;
    #pragma unroll
    for (int kk = 0; kk < 4; ++kk) {
        const v8s a = *(const v8s*)(&As[arow * 136 + kk * 32 + quad * 8]);
        #pragma unroll
        for (int nt = 0; nt < NT; ++nt) {
            const v8s b = *(const v8s*)(&Ws[(nt * 16 + l15) * 136 + kk * 32 + quad * 8]);
            acc[nt] = __builtin_amdgcn_mfma_f32_16x16x32_bf16(a, b, acc[nt], 0, 0, 0);
        }
    }

    const long long mbase = m0 + wave * 16 + quad * 4;
    const int b = (int)(m0 / NQC);             // 64 | NQC
    #pragma unroll
    for (int nt = 0; nt < 8; ++nt) {           // value: h = nt, dh = l15
        const float bi = bias[nt * 16 + l15];
        #pragma unroll
        for (int r = 0; r < 4; ++r) {
            const long long q = (mbase + r) - (long long)b * NQC;
            value[((long long)(b * HEADS + nt) * NQC + q) * DH + l15] =
                f2bb(acc[nt][r] + bi);
        }
    }
    #pragma unroll
    for (int nt = 8; nt < 14; ++nt) {          // proj cols (nt-8)*16 + l15
        const float bi = bias[nt * 16 + l15];
        #pragma unroll
        for (int r = 0; r < 4; ++r)
            proj[(mbase + r) * 96 + (nt - 8) * 16 + l15] = f2bb(acc[nt][r] + bi);
    }
}

// ---------------------------------------------------------------------------
// Legacy GEMM template (fallback path only). MODE 0: value-layout bf16 out.
// MODE 2: fp32 in-place + b + 2*query.
// ---------------------------------------------------------------------------
template<int NT, int MODE>
__global__ __launch_bounds__(256) void gemm_kernel(
    const float* __restrict__ A,
    const unsigned short* __restrict__ Wt,
    const float* __restrict__ bias,
    unsigned short* __restrict__ dst_bf,
    float* __restrict__ dst_f,
    const float* __restrict__ query)
{
    constexpr int NC = NT * 16;
    __shared__ unsigned short As[64 * 136];
    __shared__ unsigned short Ws[NC * 136];
    const int t = threadIdx.x;
    const long long m0 = (long long)blockIdx.x * 64;

    {
        const float4* src = (const float4*)(A + m0 * DD);
        #pragma unroll
        for (int rep = 0; rep < 8; ++rep) {
            const int c = rep * 256 + t;
            const int m = c >> 5, f4 = c & 31;
            const float4 v = src[c];
            ushort4 hq;
            hq.x = f2bb(v.x); hq.y = f2bb(v.y); hq.z = f2bb(v.z); hq.w = f2bb(v.w);
            *(ushort4*)(&As[m * 136 + f4 * 4]) = hq;
        }
    }
    {
        const uint4* src = (const uint4*)Wt;
        for (int c = t; c < NC * 16; c += 256) {
            const int n = c >> 4, kc = c & 15;
            *(uint4*)(&Ws[n * 136 + kc * 8]) = src[c];
        }
    }
    __syncthreads();

    const int lane = t & 63, wave = t >> 6;
    const int l15 = lane & 15, quad = lane >> 4;

    v4f acc[NT];
    #pragma unroll
    for (int nt = 0; nt < NT; ++nt) { v4f z = {0.f, 0.f, 0.f, 0.f}; acc[nt] = z; }

    const int arow = wave * 16 + l15;
    #pragma unroll
    for (int kk = 0; kk < 4; ++kk) {
        const v8s a = *(const v8s*)(&As[arow * 136 + kk * 32 + quad * 8]);
        #pragma unroll
        for (int nt = 0; nt < NT; ++nt) {
            const v8s b = *(const v8s*)(&Ws[(nt * 16 + l15) * 136 + kk * 32 + quad * 8]);
            acc[nt] = __builtin_amdgcn_mfma_f32_16x16x32_bf16(a, b, acc[nt], 0, 0, 0);
        }
    }

    const long long mbase = m0 + wave * 16 + quad * 4;
    if (MODE == 0) {
        const int b = (int)(m0 / NQC);
        #pragma unroll
        for (int nt = 0; nt < NT; ++nt) {
            const float bi = bias[nt * 16 + l15];
            #pragma unroll
            for (int r = 0; r < 4; ++r) {
                const long long q = (mbase + r) - (long long)b * NQC;
                dst_bf[((long long)(b * HEADS + nt) * NQC + q) * DH + l15] =
                    f2bb(acc[nt][r] + bi);
            }
        }
    } else {
        #pragma unroll
        for (int nt = 0; nt < NT; ++nt) {
            const float bi = bias[nt * 16 + l15];
            #pragma unroll
            for (int r = 0; r < 4; ++r) {
                const long long idx = (mbase + r) * DD + nt * 16 + l15;
                dst_f[idx] = acc[nt][r] + bi + 2.0f * query[idx];
            }
        }
    }
}

// ---------------------------------------------------------------------------
// Merged sampler + output GEMM, v2 (occupancy fix).
// 4112 blocks x 256 threads, 64 queries/block.
// Phase 1: stage proj tile as bf16 (12.3 KB, was fp32 24.6 KB).
// Phase 2: 8 gather iterations -> bf16 attn tile As[64][136] (MFMA A layout).
// Phase 3: MFMA with B streamed from global in fragment order (WtOf,
// coalesced 1 KB/wave loads, L2-resident) — no Ws LDS, no 3rd barrier.
// LDS: 12288 + 17408 = 29696 B -> 5 blocks/CU (20 waves, 62.5%) vs 3 (30%).
// ---------------------------------------------------------------------------
__global__ __launch_bounds__(256) void sample_out_kernel(
    const unsigned short* __restrict__ proj,   // [M][96] bf16
    const unsigned short* __restrict__ value,  // [16][NQC][16] bf16
    const unsigned short* __restrict__ WtOf,   // fragment-ordered [4][8][64][8]
    const float* __restrict__ bout,            // [128]
    const float* __restrict__ query,
    float* __restrict__ out)
{
    __shared__ unsigned short projS[64 * 96];  // 12288 B, bf16
    __shared__ unsigned short As[64 * 136];    // 17408 B

    const int t = threadIdx.x;
    const long long qbase = (long long)blockIdx.x * 64;

    // ---- Phase 1: stage proj (64x96 bf16, flat copy 768 uint4) ----
    {
        const uint4* src = (const uint4*)(proj + qbase * 96);
        #pragma unroll
        for (int rep = 0; rep < 3; ++rep) {
            const int i = rep * 256 + t;
            *(uint4*)(&projS[i * 8]) = src[i];
        }
    }
    __syncthreads();

    // ---- Phase 2: gather. 2048 lane-tasks, 8 per thread ----
    const int b = (int)(qbase / NQC);          // 64 | NQC: no straddle
    const int lq = t & 31;
    const int h = lq >> 2, p_own = lq & 3;
    const int lbase = (t & 63) & ~3;
    const unsigned short* V = value + (size_t)(b * HEADS + h) * NQC * DH + p_own * 4;

    #pragma unroll
    for (int it = 0; it < 8; ++it) {
        const int q_loc = it * 8 + (t >> 5);
        const int qidx = (int)(qbase - (long long)b * NQC) + q_loc;
        const int row = qidx >> 9, col = qidx & 511;

        // (h*PTS+p_own)*2 == lq*2 ; attn logits at 64+lq
        const float offx = bb2f(projS[q_loc * 96 + lq * 2]);
        const float offy = bb2f(projS[q_loc * 96 + lq * 2 + 1]);
        const float al   = bb2f(projS[q_loc * 96 + 64 + lq]);
        float mx = fmaxf(al, __shfl_xor(al, 1));
        mx = fmaxf(mx, __shfl_xor(mx, 2));
        const float e = __expf(al - mx);
        float sm = e + __shfl_xor(e, 1);
        sm += __shfl_xor(sm, 2);
        const float aw = e / sm;

        const float x = (float)col * (1.0f / 511.0f) * (float)W_LVL + offx - 0.5f;
        const float y = (float)row * (1.0f / 256.0f) * (float)H_LVL + offy - 0.5f;
        const float x0f = floorf(x), y0f = floorf(y);
        const int x0 = (int)x0f, y0 = (int)y0f;
        const int x1 = x0 + 1, y1 = y0 + 1;
        const float wx1 = x - x0f, wx0 = 1.0f - wx1;
        const float wy1 = y - y0f, wy0 = 1.0f - wy1;
        const float vx0 = (x0 >= 0 && x0 < W_LVL) ? 1.f : 0.f;
        const float vx1 = (x1 >= 0 && x1 < W_LVL) ? 1.f : 0.f;
        const float vy0 = (y0 >= 0 && y0 < H_LVL) ? 1.f : 0.f;
        const float vy1 = (y1 >= 0 && y1 < H_LVL) ? 1.f : 0.f;
        float w00 = aw * wx0 * wy0 * vx0 * vy0;
        float w01 = aw * wx1 * wy0 * vx1 * vy0;
        float w10 = aw * wx0 * wy1 * vx0 * vy1;
        float w11 = aw * wx1 * wy1 * vx1 * vy1;
        const int xc0 = min(max(x0, 0), W_LVL - 1), xc1 = min(max(x1, 0), W_LVL - 1);
        const int yc0 = min(max(y0, 0), H_LVL - 1), yc1 = min(max(y1, 0), H_LVL - 1);
        int i00 = yc0 * W_LVL + xc0, i01 = yc0 * W_LVL + xc1;
        int i10 = yc1 * W_LVL + xc0, i11 = yc1 * W_LVL + xc1;

        float4 acc = {0.f, 0.f, 0.f, 0.f};
        #pragma unroll
        for (int p = 0; p < 4; ++p) {
            const int src = lbase + p;
            const float W00 = __shfl(w00, src, 64), W01 = __shfl(w01, src, 64);
            const float W10 = __shfl(w10, src, 64), W11 = __shfl(w11, src, 64);
            const int   I00 = __shfl(i00, src, 64), I01 = __shfl(i01, src, 64);
            const int   I10 = __shfl(i10, src, 64), I11 = __shfl(i11, src, 64);
            fma4(acc, W00, V + (size_t)I00 * DH);
            fma4(acc, W01, V + (size_t)I01 * DH);
            fma4(acc, W10, V + (size_t)I10 * DH);
            fma4(acc, W11, V + (size_t)I11 * DH);
        }
        ushort4 h4;
        h4.x = f2bb(acc.x); h4.y = f2bb(acc.y); h4.z = f2bb(acc.z); h4.w = f2bb(acc.w);
        *(ushort4*)(&As[q_loc * 136 + lq * 4]) = h4;   // h*16+p_own*4 == lq*4
    }
    __syncthreads();

    // ---- Phase 3: MFMA, B streamed from global (fragment order) ----
    const int lane = t & 63, wave = t >> 6;
    const int l15 = lane & 15, quad = lane >> 4;

    v4f acc[8];
    #pragma unroll
    for (int nt = 0; nt < 8; ++nt) { v4f z = {0.f, 0.f, 0.f, 0.f}; acc[nt] = z; }

    const int arow = wave * 16 + l15;
    #pragma unroll
    for (int kk = 0; kk < 4; ++kk) {
        const v8s a = *(const v8s*)(&As[arow * 136 + kk * 32 + quad * 8]);
        #pragma unroll
        for (int nt = 0; nt < 8; ++nt) {
            const v8s bfr = *(const v8s*)(WtOf + (size_t)((kk * 8 + nt) * 64 + lane) * 8);
            acc[nt] = __builtin_amdgcn_mfma_f32_16x16x32_bf16(a, bfr, acc[nt], 0, 0, 0);
        }
    }

    const long long mbase = qbase + wave * 16 + quad * 4;
    #pragma unroll
    for (int nt = 0; nt < 8; ++nt) {
        const float bi = bout[nt * 16 + l15];
        #pragma unroll
        for (int r = 0; r < 4; ++r) {
            const long long idx = (mbase + r) * DD + nt * 16 + l15;
            out[idx] = acc[nt][r] + bi + 2.0f * query[idx];
        }
    }
}

// ---------------------------------------------------------------------------
// Fallback sampler (no precomp workspace): fp32 out, on-the-fly proj.
// ---------------------------------------------------------------------------
__global__ __launch_bounds__(256) void sample2_fb_kernel(
    const float* __restrict__ query,
    const float* __restrict__ Woff, const float* __restrict__ boff,
    const float* __restrict__ Wattn, const float* __restrict__ battn,
    const unsigned short* __restrict__ value,  // [16][NQC][16] bf16
    float* __restrict__ attn_out)
{
    __shared__ float projF[8][96];
    const int t = threadIdx.x;
    const long long qbase = (long long)blockIdx.x * 8;

    __shared__ float qs[8][DD];
    {
        const int qi = t >> 5, k4 = (t & 31) * 4;
        const float4 v = *(const float4*)(query + (qbase + qi) * DD + k4);
        qs[qi][k4] = v.x; qs[qi][k4 + 1] = v.y; qs[qi][k4 + 2] = v.z; qs[qi][k4 + 3] = v.w;
    }
    __syncthreads();
    for (int task = t; task < 768; task += 256) {
        const int qi = task / 96, c = task % 96;
        float a; const float* wp; int stride;
        if (c < 64) { a = boff[c];       wp = Woff  + c;        stride = 64; }
        else        { a = battn[c - 64]; wp = Wattn + (c - 64); stride = 32; }
        for (int k = 0; k < DD; ++k) a += qs[qi][k] * wp[k * stride];
        projF[qi][c] = a;
    }
    __syncthreads();

    const int q_loc = t >> 5, lq = t & 31;
    const int h = lq >> 2, p_own = lq & 3;
    const long long bq = qbase + q_loc;
    const int b = (int)(bq / NQC);
    const int qidx = (int)(bq - (long long)b * NQC);
    const int row = qidx >> 9, col = qidx & 511;

    const float offx = projF[q_loc][(h * PTS + p_own) * 2];
    const float offy = projF[q_loc][(h * PTS + p_own) * 2 + 1];
    const float al   = projF[q_loc][64 + h * PTS + p_own];
    float mx = fmaxf(al, __shfl_xor(al, 1));
    mx = fmaxf(mx, __shfl_xor(mx, 2));
    const float e = __expf(al - mx);
    float sm = e + __shfl_xor(e, 1);
    sm += __shfl_xor(sm, 2);
    const float aw = e / sm;

    const float x = (float)col * (1.0f / 511.0f) * (float)W_LVL + offx - 0.5f;
    const float y = (float)row * (1.0f / 256.0f) * (float)H_LVL + offy - 0.5f;
    const float x0f = floorf(x), y0f = floorf(y);
    const int x0 = (int)x0f, y0 = (int)y0f;
    const int x1 = x0 + 1, y1 = y0 + 1;
    const float wx1 = x - x0f, wx0 = 1.0f - wx1;
    const float wy1 = y - y0f, wy0 = 1.0f - wy1;
    const float vx0 = (x0 >= 0 && x0 < W_LVL) ? 1.f : 0.f;
    const float vx1 = (x1 >= 0 && x1 < W_LVL) ? 1.f : 0.f;
    const float vy0 = (y0 >= 0 && y0 < H_LVL) ? 1.f : 0.f;
    const float vy1 = (y1 >= 0 && y1 < H_LVL) ? 1.f : 0.f;
    float w00 = aw * wx0 * wy0 * vx0 * vy0;
    float w01 = aw * wx1 * wy0 * vx1 * vy0;
    float w10 = aw * wx0 * wy1 * vx0 * vy1;
    float w11 = aw * wx1 * wy1 * vx1 * vy1;
    const int xc0 = min(max(x0, 0), W_LVL - 1), xc1 = min(max(x1, 0), W_LVL - 1);
    const int yc0 = min(max(y0, 0), H_LVL - 1), yc1 = min(max(y1, 0), H_LVL - 1);
    int i00 = yc0 * W_LVL + xc0, i01 = yc0 * W_LVL + xc1;
    int i10 = yc1 * W_LVL + xc0, i11 = yc1 * W_LVL + xc1;

    const int dq4 = p_own;
    const unsigned short* V = value + (size_t)(b * HEADS + h) * NQC * DH + dq4 * 4;
    float4 acc = {0.f, 0.f, 0.f, 0.f};
    const int lbase = (t & 63) & ~3;
    #pragma unroll
    for (int p = 0; p < 4; ++p) {
        const int src = lbase + p;
        const float W00 = __shfl(w00, src, 64), W01 = __shfl(w01, src, 64);
        const float W10 = __shfl(w10, src, 64), W11 = __shfl(w11, src, 64);
        const int   I00 = __shfl(i00, src, 64), I01 = __shfl(i01, src, 64);
        const int   I10 = __shfl(i10, src, 64), I11 = __shfl(i11, src, 64);
        fma4(acc, W00, V + (size_t)I00 * DH);
        fma4(acc, W01, V + (size_t)I01 * DH);
        fma4(acc, W10, V + (size_t)I10 * DH);
        fma4(acc, W11, V + (size_t)I11 * DH);
    }
    *(float4*)(attn_out + bq * DD + h * DH + dq4 * 4) = acc;
}

// ---------------------------------------------------------------------------
extern "C" void kernel_launch(void* const* d_in, const int* in_sizes, int n_in,
                              void* d_out, int out_size, void* d_ws, size_t ws_size,
                              hipStream_t stream) {
    const float* query = (const float*)d_in[0];
    const float* Wv    = (const float*)d_in[1];
    const float* bv    = (const float*)d_in[2];
    const float* Woff  = (const float*)d_in[3];
    const float* boff  = (const float*)d_in[4];
    const float* Wattn = (const float*)d_in[5];
    const float* battn = (const float*)d_in[6];
    const float* Wout  = (const float*)d_in[7];
    const float* bout  = (const float*)d_in[8];
    float* out = (float*)d_out;

    char* ws = (char*)d_ws;
    size_t off = 0;
    unsigned short* Wt224 = (unsigned short*)(ws + off); off += 224 * 128 * 2;
    unsigned short* WtO   = (unsigned short*)(ws + off); off += 128 * 128 * 2;
    unsigned short* WtOf  = (unsigned short*)(ws + off); off += 128 * 128 * 2;
    float*          bcat  = (float*)(ws + off);          off += 224 * 4;
    off = (off + 255) & ~(size_t)255;
    unsigned short* value = (unsigned short*)(ws + off);
    off += (size_t)BS * HEADS * NQC * DH * 2;            // 67,371,008 B
    off = (off + 255) & ~(size_t)255;
    unsigned short* proj = (unsigned short*)(ws + off);
    const size_t proj_need = (size_t)MTOT * 96 * 2;      // 50,528,256 B
    const bool precomp = (ws_size >= off + proj_need);

    prep_kernel<<<112, 256, 0, stream>>>(Wv, bv, Woff, boff, Wattn, battn, Wout,
                                         Wt224, WtO, WtOf, bcat);
    if (precomp) {
        gemm_fused_kernel<<<MTOT / 64, 256, 0, stream>>>(query, Wt224, bcat, value, proj);
        sample_out_kernel<<<MTOT / 64, 256, 0, stream>>>(proj, value, WtOf, bout, query, out);
    } else {
        gemm_kernel<8, 0><<<MTOT / 64, 256, 0, stream>>>(query, Wt224, bcat, value,
                                                         nullptr, nullptr);
        sample2_fb_kernel<<<MTOT / 8, 256, 0, stream>>>(query, Woff, boff,
                                                        Wattn, battn, value, out);
        gemm_kernel<8, 2><<<MTOT / 64, 256, 0, stream>>>(out, WtO, bout, nullptr, out, query);
    }
}